// Round 8
// baseline (512.395 us; speedup 1.0000x reference)
//
#include <hip/hip_runtime.h>
#include <hip/hip_bf16.h>
#include <math.h>

#define BB 8192
#define FF 32
#define DD 128
#define HH 128
#define FD 4096   // F*D
#define E2 256    // 2*D
#define F2 8192   // 2*FD
#define LN_EPS 1e-5f
#define L2E 1.44269504f
#define KSPLIT 8
#define LSLICE 8

typedef __hip_bfloat16 bf16;
typedef __attribute__((ext_vector_type(8))) short bf16x8;
typedef __attribute__((ext_vector_type(4))) float f32x4;

__device__ __forceinline__ float s2f(short s) {
  union { float f; unsigned u; } x; x.u = ((unsigned)(unsigned short)s) << 16; return x.f;
}
__device__ __forceinline__ short f2s(float v) {
  bf16 h = __float2bfloat16(v); return *(short*)&h;
}
__device__ __forceinline__ float fast_sigmoid(float s) {
  return __builtin_amdgcn_rcpf(1.f + __builtin_amdgcn_exp2f(-L2E * s));
}
__device__ __forceinline__ float fast_elu(float v) {
  return v > 0.f ? v : __builtin_amdgcn_exp2f(L2E * v) - 1.f;
}

// byte offset into a [rows][64] bf16 tile (128B rows) with XOR swizzle; hb = byte offset
// within row (multiple of 16). Keeps 16B alignment for b128 ops, spreads 16-lane column
// reads across 8 distinct 16B slots per 8-row stripe (T2 / G4 pattern).
__device__ __forceinline__ int swz64(int row, int hb) {
  return row * 128 + (hb ^ ((row & 7) << 4));
}
// short-index swizzle for a [rows][64]-short tile: col ^= (row&7)<<3
__device__ __forceinline__ int swzs(int row, int cs) {
  return row * 64 + (cs ^ ((row & 7) << 3));
}

// ---------------- prep kernels (inputs fp32) ----------------

__global__ void prep_A1(const float* __restrict__ Wp, const float* __restrict__ bp,
                        const float* __restrict__ fW1, const float* __restrict__ fb1,
                        float* __restrict__ A1, float* __restrict__ C1) {
  int f = blockIdx.x, h = threadIdx.x;
  const float* w1 = fW1 + (size_t)f * DD * HH;
  float a = 0.f, c = 0.f;
  for (int d = 0; d < DD; ++d) {
    float w = w1[d * HH + h];
    a += Wp[f * DD + d] * w;
    c += bp[f * DD + d] * w;
  }
  A1[f * HH + h] = a;
  C1[f * HH + h] = c + fb1[f * HH + h];
}

__global__ void prep_M2(const float* __restrict__ fW2, const float* __restrict__ fWg,
                        float* __restrict__ M2) {
  int f = blockIdx.x, h = blockIdx.y, e = threadIdx.x;
  const float* w2 = fW2 + ((size_t)f * HH + h) * DD;
  const float* wg = fWg + (size_t)f * DD * E2;
  float acc = 0.f;
  for (int d = 0; d < DD; ++d) acc += w2[d] * wg[d * E2 + e];
  M2[((size_t)f * HH + h) * E2 + e] = acc;
}

// M2 [f][h][e] fp32 -> M2T [f][e][h] bf16 (float4 loads, bf16x8 stores)
__global__ void m2_castT(const float* __restrict__ M2, short* __restrict__ M2T) {
  __shared__ float T[64][65];
  int h0 = blockIdx.x * 64, e0 = blockIdx.y * 64, f = blockIdx.z;
  int t = threadIdx.x;
  for (int i = 0; i < 4; ++i) {
    int lin = t + 256 * i;
    int r = lin >> 4, c4 = (lin & 15) * 4;
    f32x4 v = *(const f32x4*)&M2[((size_t)f * HH + h0 + r) * E2 + e0 + c4];
    T[r][c4] = v[0]; T[r][c4 + 1] = v[1]; T[r][c4 + 2] = v[2]; T[r][c4 + 3] = v[3];
  }
  __syncthreads();
  for (int i = 0; i < 2; ++i) {
    int lin = t + 256 * i;
    int e = lin >> 3, h8 = (lin & 7) * 8;
    short o[8];
    for (int k = 0; k < 8; ++k) o[k] = f2s(T[h8 + k][e]);
    *(bf16x8*)&M2T[((size_t)f * E2 + e0 + e) * HH + h0 + h8] = *(bf16x8*)&o[0];
  }
}

__global__ void prep_c2(const float* __restrict__ fb2, const float* __restrict__ fWg,
                        const float* __restrict__ fbg, float* __restrict__ c2) {
  int f = blockIdx.x, e = threadIdx.x;
  const float* wg = fWg + (size_t)f * DD * E2;
  float acc = 0.f;
  for (int d = 0; d < DD; ++d) acc += fb2[f * DD + d] * wg[d * E2 + e];
  c2[f * E2 + e] = acc + fbg[f * E2 + e];
}

__global__ void cast_bf16(const float* __restrict__ in, short* __restrict__ out, int n) {
  int i = blockIdx.x * 256 + threadIdx.x;
  if (i < n) out[i] = f2s(in[i]);
}

// transpose-cast: in (R x C) fp32 -> out (C x R) bf16 (float4 loads, bf16x8 stores)
__global__ void castT(const float* __restrict__ in, short* __restrict__ out, int R, int C) {
  __shared__ float T[64][65];
  int c0 = blockIdx.x * 64, r0 = blockIdx.y * 64;
  int t = threadIdx.x;
  for (int i = 0; i < 4; ++i) {
    int lin = t + 256 * i;
    int r = lin >> 4, c4 = (lin & 15) * 4;
    f32x4 v = *(const f32x4*)&in[(size_t)(r0 + r) * C + c0 + c4];
    T[r][c4] = v[0]; T[r][c4 + 1] = v[1]; T[r][c4 + 2] = v[2]; T[r][c4 + 3] = v[3];
  }
  __syncthreads();
  for (int i = 0; i < 2; ++i) {
    int lin = t + 256 * i;
    int c = lin >> 3, r8 = (lin & 7) * 8;
    short o[8];
    for (int e = 0; e < 8; ++e) o[e] = f2s(T[r8 + e][c]);
    *(bf16x8*)&out[(size_t)(c0 + c) * R + r0 + r8] = *(bf16x8*)&o[0];
  }
}

// merged tiny inits: lpart = 0 (2M floats); c3 = sbg; rowstats = 0; u = 0; w0 = bh
// v9: grid is LSLICE*BB*FF/256 = 8192 blocks.
__global__ void init_misc(const float* __restrict__ sbg, const float* __restrict__ bh,
                          float* __restrict__ c3, float* __restrict__ rowstats,
                          float* __restrict__ u, float* __restrict__ w0,
                          float* __restrict__ lpart) {
  int j = blockIdx.x * 256 + threadIdx.x;
  lpart[j] = 0.f;
  if (j < F2) c3[j] = sbg[j];
  if (j < 2 * BB) rowstats[j] = 0.f;
  if (j < 32) { u[j] = 0.f; w0[j] = bh[j]; }
}

// transpose-cast sWg (4096 x 8192) -> sWgT (8192 x 4096) bf16, fused c3 += sb2 @ sWg
__global__ void castT_c3(const float* __restrict__ in, short* __restrict__ out,
                         const float* __restrict__ sb2, float* __restrict__ c3) {
  __shared__ float T[64][65];
  int c0 = blockIdx.x * 64, r0 = blockIdx.y * 64;
  int t = threadIdx.x;
  for (int i = 0; i < 4; ++i) {
    int lin = t + 256 * i;
    int r = lin >> 4, c4 = (lin & 15) * 4;
    f32x4 v = *(const f32x4*)&in[(size_t)(r0 + r) * F2 + c0 + c4];
    T[r][c4] = v[0]; T[r][c4 + 1] = v[1]; T[r][c4 + 2] = v[2]; T[r][c4 + 3] = v[3];
  }
  __syncthreads();
  for (int i = 0; i < 2; ++i) {
    int lin = t + 256 * i;
    int c = lin >> 3, r8 = (lin & 7) * 8;
    short o[8];
    for (int e = 0; e < 8; ++e) o[e] = f2s(T[r8 + e][c]);
    *(bf16x8*)&out[(size_t)(c0 + c) * FD + r0 + r8] = *(bf16x8*)&o[0];
  }
  if (t < 64) {
    float s = 0.f;
    for (int r = 0; r < 64; ++r) s += sb2[r0 + r] * T[r][t];
    atomicAdd(&c3[c0 + t], s);
  }
}

// WhS = (sg*Wh)^T bf16; u += sg.Wh col-sums; w0 += sbe.Wh col-sums
__global__ void prep_whs(const float* __restrict__ Wh, const float* __restrict__ sg,
                         const float* __restrict__ sbe, short* __restrict__ WhS,
                         float* __restrict__ u, float* __restrict__ w0) {
  __shared__ float T[64][33];
  int k0 = blockIdx.x * 64;
  int t = threadIdx.x;
  {
    int k = t >> 5, c = t & 31;
    for (int i = 0; i < 8; ++i)
      T[k + 8 * i][c] = Wh[(size_t)(k0 + k + 8 * i) * FF + c];
  }
  __syncthreads();
  {
    int c = t >> 3, kk = (t & 7) * 8;
    short o[8];
    for (int i = 0; i < 8; ++i) o[i] = f2s(sg[k0 + kk + i] * T[kk + i][c]);
    *(bf16x8*)&WhS[(size_t)c * FD + k0 + kk] = *(bf16x8*)&o[0];
  }
  if (t < 32) {
    float su = 0.f, sw = 0.f;
    for (int k = 0; k < 64; ++k) { su += sg[k0 + k] * T[k][t]; sw += sbe[k0 + k] * T[k][t]; }
    atomicAdd(&u[t], su);
    atomicAdd(&w0[t], sw);
  }
}

// ---------------- MFMA GEMM: C[M,128] = A[M,K] @ BT[128,K]^T, split-K by 8 ----------------
__global__ __launch_bounds__(256) void gemm_bt_n128_splitk(
    const short* __restrict__ A, const short* __restrict__ BT,
    float* __restrict__ Cp, int M, int K) {
  __shared__ short As[128 * 72];
  __shared__ short Bs[128 * 72];
  int m0 = blockIdx.x * 128;
  int kchunk = K >> 3;
  int kbase = blockIdx.y * kchunk;
  int tid = threadIdx.x;
  int lane = tid & 63, w = tid >> 6;
  int wm = (w >> 1) * 64, wn = (w & 1) * 64;
  int lm = lane & 15, lq = lane >> 4;
  f32x4 acc[4][4] = {};
  for (int kc = 0; kc < kchunk; kc += 64) {
    for (int i = 0; i < 4; ++i) {
      int li = tid + 256 * i;
      int r = li >> 3, c8 = (li & 7) * 8;
      *(bf16x8*)&As[r * 72 + c8] = *(const bf16x8*)&A[(size_t)(m0 + r) * K + kbase + kc + c8];
      *(bf16x8*)&Bs[r * 72 + c8] = *(const bf16x8*)&BT[(size_t)r * K + kbase + kc + c8];
    }
    __syncthreads();
    for (int ks = 0; ks < 2; ++ks) {
      bf16x8 af[4], bfr[4];
      for (int i = 0; i < 4; ++i)
        af[i] = *(const bf16x8*)&As[(wm + i * 16 + lm) * 72 + ks * 32 + lq * 8];
      for (int j = 0; j < 4; ++j)
        bfr[j] = *(const bf16x8*)&Bs[(wn + j * 16 + lm) * 72 + ks * 32 + lq * 8];
      for (int i = 0; i < 4; ++i)
        for (int j = 0; j < 4; ++j)
          acc[i][j] = __builtin_amdgcn_mfma_f32_16x16x32_bf16(af[i], bfr[j], acc[i][j], 0, 0, 0);
    }
    __syncthreads();
  }
  float* out = Cp + (size_t)blockIdx.y * M * 128;
  for (int i = 0; i < 4; ++i)
    for (int j = 0; j < 4; ++j)
      for (int v = 0; v < 4; ++v) {
        int r = wm + i * 16 + lq * 4 + v;
        int c = wn + j * 16 + lm;
        out[(size_t)(m0 + r) * 128 + c] = acc[i][j][v];
      }
}

__global__ void reduce_m3t(const float* __restrict__ Cp, short* __restrict__ M3T, int M) {
  size_t i = (size_t)blockIdx.x * 256 + threadIdx.x;
  float s = 0.f;
  for (int k = 0; k < KSPLIT; ++k) s += Cp[(size_t)k * M * 128 + i];
  M3T[i] = f2s(s);
}

__global__ void reduce_hh1(const float* __restrict__ Cp, const float* __restrict__ sb1,
                           short* __restrict__ hh1, int M) {
  size_t i = (size_t)blockIdx.x * 256 + threadIdx.x;
  float s = 0.f;
  for (int k = 0; k < KSPLIT; ++k) s += Cp[(size_t)k * M * 128 + i];
  s += sb1[i & 127];
  hh1[i] = f2s(fast_elu(s));
}

// ---------------- stage A (MFMA): h1 = elu(x*A1+C1); gates = h1@M2; LN -> stacked ----------------
// v8 structure: two-pass B time-share, one 16KB B-buffer, af held in regs across passes.
// No launch-bound clamp (v2/v4 lesson: clamping this kernel always spills).
__global__ __launch_bounds__(256) void stageA_mfma(
    const float* __restrict__ x, const float* __restrict__ Wp,
    const float* __restrict__ bp, const float* __restrict__ A1,
    const float* __restrict__ C1, const short* __restrict__ M2T,
    const float* __restrict__ c2, const float* __restrict__ fg,
    const float* __restrict__ fbe, short* __restrict__ stacked) {
  __shared__ __align__(16) char SM[(64 + 128) * 128];  // As(8K) | Bs(16K)
  char* As = SM;
  char* Bs = SM + 64 * 128;
  short* Co = (short*)(SM + 64 * 128); // epilogue 64x128 bf16 tile (16KB) aliases Bs
  float* red = (float*)SM;             // epilogue [2][64][2] stats (1KB) aliases As
  __shared__ float xsh[64];
  int f = blockIdx.y;
  int m0 = blockIdx.x * 64;
  int tid = threadIdx.x;
  int lane = tid & 63, w = tid >> 6;
  int wm = (w >> 1) * 32, wn = (w & 1) * 64;
  int lm = lane & 15, lq = lane >> 4;
  if (tid < 64) xsh[tid] = x[(size_t)(m0 + tid) * FF + f];
  __syncthreads();
  f32x4 accA[2][4] = {}, accB[2][4] = {};
  int c8 = (tid & 7) * 8, rb = tid >> 3;   // As-gen ownership: 8 cols x 2 rows per thread
  for (int kc = 0; kc < HH; kc += 64) {
    // --- As-gen: h1 = elu(x*A1+C1); A1/C1 chunk loaded once as float4 ---
    {
      f32x4 a1lo = *(const f32x4*)&A1[f * HH + kc + c8];
      f32x4 a1hi = *(const f32x4*)&A1[f * HH + kc + c8 + 4];
      f32x4 c1lo = *(const f32x4*)&C1[f * HH + kc + c8];
      f32x4 c1hi = *(const f32x4*)&C1[f * HH + kc + c8 + 4];
      for (int rr = 0; rr < 2; ++rr) {
        int row = rb + rr * 32;
        float xr = xsh[row];
        short o[8];
        for (int e = 0; e < 4; ++e) {
          o[e]     = f2s(fast_elu(fmaf(xr, a1lo[e], c1lo[e])));
          o[e + 4] = f2s(fast_elu(fmaf(xr, a1hi[e], c1hi[e])));
        }
        *(bf16x8*)(As + swz64(row, c8 * 2)) = *(bf16x8*)&o[0];
      }
    }
    // --- stage Ba (first E2 half) into Bs ---
    for (int i = 0; i < 4; ++i) {
      int li = tid + 256 * i;
      int r = li >> 3, cc = (li & 7) * 8;
      bf16x8 va = *(const bf16x8*)&M2T[((size_t)f * E2 + r) * HH + kc + cc];
      *(bf16x8*)(Bs + swz64(r, cc * 2)) = va;
    }
    __syncthreads();
    // hold A-fragments for both ks in regs (reused for the Bb pass)
    bf16x8 af[2][2];
    for (int ks = 0; ks < 2; ++ks)
      for (int i = 0; i < 2; ++i)
        af[ks][i] = *(const bf16x8*)(As + swz64(wm + i * 16 + lm, ks * 64 + lq * 16));
    for (int ks = 0; ks < 2; ++ks) {
      int hb = ks * 64 + lq * 16;
      for (int j = 0; j < 4; ++j) {
        bf16x8 ba = *(const bf16x8*)(Bs + swz64(wn + j * 16 + lm, hb));
        for (int i = 0; i < 2; ++i)
          accA[i][j] = __builtin_amdgcn_mfma_f32_16x16x32_bf16(af[ks][i], ba, accA[i][j], 0, 0, 0);
      }
    }
    __syncthreads();
    // --- stage Bb (second E2 half) into the SAME buffer ---
    for (int i = 0; i < 4; ++i) {
      int li = tid + 256 * i;
      int r = li >> 3, cc = (li & 7) * 8;
      bf16x8 vb = *(const bf16x8*)&M2T[((size_t)f * E2 + 128 + r) * HH + kc + cc];
      *(bf16x8*)(Bs + swz64(r, cc * 2)) = vb;
    }
    __syncthreads();
    for (int ks = 0; ks < 2; ++ks) {
      int hb = ks * 64 + lq * 16;
      for (int j = 0; j < 4; ++j) {
        bf16x8 bb = *(const bf16x8*)(Bs + swz64(wn + j * 16 + lm, hb));
        for (int i = 0; i < 2; ++i)
          accB[i][j] = __builtin_amdgcn_mfma_f32_16x16x32_bf16(af[ks][i], bb, accB[i][j], 0, 0, 0);
      }
    }
    __syncthreads();
  }
  // --- epilogue: gating + LN stats (batched butterfly) ---
  float c2a[4], c2s[4], wpv[4], bpv[4];
  for (int j = 0; j < 4; ++j) {
    int c = wn + j * 16 + lm;
    c2a[j] = c2[f * E2 + c];
    c2s[j] = c2[f * E2 + 128 + c];
    wpv[j] = Wp[f * DD + c];
    bpv[j] = bp[f * DD + c];
  }
  float rs[2][4], rq[2][4];
  for (int i = 0; i < 2; ++i)
    for (int v = 0; v < 4; ++v) {
      int r = wm + i * 16 + lq * 4 + v;
      float xr = xsh[r];
      float sum = 0.f, sq = 0.f;
      for (int j = 0; j < 4; ++j) {
        float a = accA[i][j][v] + c2a[j];
        float s = accB[i][j][v] + c2s[j];
        float emb = fmaf(xr, wpv[j], bpv[j]);
        float y = fmaf(a, fast_sigmoid(s), emb);
        accA[i][j][v] = y;  // stash y
        sum += y; sq += y * y;
      }
      rs[i][v] = sum; rq[i][v] = sq;
    }
  for (int m = 1; m < 16; m <<= 1)
    for (int i = 0; i < 2; ++i)
      for (int v = 0; v < 4; ++v) {
        rs[i][v] += __shfl_xor(rs[i][v], m, 64);
        rq[i][v] += __shfl_xor(rq[i][v], m, 64);
      }
  if (lm == 0)
    for (int i = 0; i < 2; ++i)
      for (int v = 0; v < 4; ++v) {
        int r = wm + i * 16 + lq * 4 + v;
        red[(w & 1) * 128 + r * 2]     = rs[i][v];
        red[(w & 1) * 128 + r * 2 + 1] = rq[i][v];
      }
  __syncthreads();
  float fgv[4], fbev[4];
  for (int j = 0; j < 4; ++j) {
    int c = wn + j * 16 + lm;
    fgv[j] = fg[f * DD + c];
    fbev[j] = fbe[f * DD + c];
  }
  for (int i = 0; i < 2; ++i)
    for (int v = 0; v < 4; ++v) {
      int r = wm + i * 16 + lq * 4 + v;
      float tot  = red[r * 2]     + red[128 + r * 2];
      float totq = red[r * 2 + 1] + red[128 + r * 2 + 1];
      float mu = tot * (1.f / DD);
      float var = totq * (1.f / DD) - mu * mu;
      float rstd = rsqrtf(var + LN_EPS);
      for (int j = 0; j < 4; ++j) {
        int c = wn + j * 16 + lm;
        Co[r * 128 + c] = f2s((accA[i][j][v] - mu) * rstd * fgv[j] + fbev[j]);
      }
    }
  __syncthreads();
  for (int i = 0; i < 4; ++i) {
    int lin = tid + 256 * i;
    int r = lin >> 4, cc8 = (lin & 15) * 8;
    *(bf16x8*)&stacked[((size_t)(m0 + r) * FF + f) * DD + cc8] = *(bf16x8*)&Co[r * 128 + cc8];
  }
}

// ---------------- sgate MFMA + fused LN stats + fused logits ----------------
// v9: tmp is never written to global. The 128x64 tmp tile is kept in LDS (swizzled Co),
// LN partial stats go to rowstats (atomics, as v4), and the logits GEMM slice
// (tmp_tile @ WhS_slice^T, 128x32 x K=64) runs right here, atomicAdd'ing into an
// 8-slice accumulator lpart[blockIdx.y&7][b][c]. Deletes the gemm_logits pass
// (64MB tmp re-read) and sgate's 64MB tmp write.
__global__ __launch_bounds__(256) void sgate_mfma(
    const short* __restrict__ hh1, const short* __restrict__ M3T,
    const float* __restrict__ c3, const short* __restrict__ stacked,
    const short* __restrict__ WhS, float* __restrict__ rowstats,
    float* __restrict__ lpart) {
  __shared__ short As[128 * 72];
  __shared__ short Ba[64 * 72];
  __shared__ short Bb[64 * 72];
  short* Co = As;  // epilogue alias: 128x64 bf16 tile, XOR-swizzled (16KB <= 18KB)
  short* Bw = Ba;  // epilogue alias: 32x72 WhS slice
  int m0 = blockIdx.x * 128;
  int c0 = blockIdx.y * 64;
  int tid = threadIdx.x;
  int lane = tid & 63, w = tid >> 6;
  int wm = (w >> 1) * 64, wn = (w & 1) * 32;
  int lm = lane & 15, lq = lane >> 4;
  f32x4 accA[4][2] = {}, accB[4][2] = {};
  for (int kc = 0; kc < 128; kc += 64) {
    for (int i = 0; i < 4; ++i) {
      int li = tid + 256 * i;
      int r = li >> 3, c8 = (li & 7) * 8;
      *(bf16x8*)&As[r * 72 + c8] = *(const bf16x8*)&hh1[(size_t)(m0 + r) * 128 + kc + c8];
    }
    for (int i = 0; i < 2; ++i) {
      int li = tid + 256 * i;
      int r = li >> 3, c8 = (li & 7) * 8;
      *(bf16x8*)&Ba[r * 72 + c8] = *(const bf16x8*)&M3T[(size_t)(c0 + r) * 128 + kc + c8];
      *(bf16x8*)&Bb[r * 72 + c8] = *(const bf16x8*)&M3T[(size_t)(4096 + c0 + r) * 128 + kc + c8];
    }
    __syncthreads();
    for (int ks = 0; ks < 2; ++ks) {
      bf16x8 af[4], ba[2], bb[2];
      for (int i = 0; i < 4; ++i)
        af[i] = *(const bf16x8*)&As[(wm + i * 16 + lm) * 72 + ks * 32 + lq * 8];
      for (int j = 0; j < 2; ++j) {
        ba[j] = *(const bf16x8*)&Ba[(wn + j * 16 + lm) * 72 + ks * 32 + lq * 8];
        bb[j] = *(const bf16x8*)&Bb[(wn + j * 16 + lm) * 72 + ks * 32 + lq * 8];
      }
      for (int i = 0; i < 4; ++i)
        for (int j = 0; j < 2; ++j) {
          accA[i][j] = __builtin_amdgcn_mfma_f32_16x16x32_bf16(af[i], ba[j], accA[i][j], 0, 0, 0);
          accB[i][j] = __builtin_amdgcn_mfma_f32_16x16x32_bf16(af[i], bb[j], accB[i][j], 0, 0, 0);
        }
    }
    __syncthreads();
  }
  // epilogue 1: gate term -> Co (swizzled scalar writes)
  for (int i = 0; i < 4; ++i)
    for (int j = 0; j < 2; ++j)
      for (int v = 0; v < 4; ++v) {
        int rl = wm + i * 16 + lq * 4 + v;
        int cl = wn + j * 16 + lm;
        int c = c0 + cl;
        float sa = accA[i][j][v] + c3[c];
        float ss = accB[i][j][v] + c3[c + 4096];
        Co[swzs(rl, cl)] = f2s(sa * fast_sigmoid(ss));
      }
  __syncthreads();
  // epilogue 2: tmp = stacked + gate (in-place in Co), LN partial stats, stage WhS slice
  for (int i = 0; i < 4; ++i) {
    int lin = tid + 256 * i;
    int r = lin >> 3, c8 = (lin & 7) * 8;
    size_t gi = (size_t)(m0 + r) * FD + c0 + c8;
    bf16x8 sv = *(const bf16x8*)&stacked[gi];
    int ci = swzs(r, c8);
    bf16x8 av = *(bf16x8*)&Co[ci];
    short ov[8];
    float ps = 0.f, pq = 0.f;
    for (int e = 0; e < 8; ++e) {
      short o = f2s(s2f(sv[e]) + s2f(av[e]));
      ov[e] = o;
      float vb = s2f(o);         // bf16-rounded value (matches old ln_stats2 semantics)
      ps += vb; pq += vb * vb;
    }
    *(bf16x8*)&Co[ci] = *(bf16x8*)&ov[0];   // tmp tile stays in LDS
    ps += __shfl_xor(ps, 1, 64); pq += __shfl_xor(pq, 1, 64);
    ps += __shfl_xor(ps, 2, 64); pq += __shfl_xor(pq, 2, 64);
    ps += __shfl_xor(ps, 4, 64); pq += __shfl_xor(pq, 4, 64);
    if ((tid & 7) == 0) {
      atomicAdd(&rowstats[2 * (m0 + r)], ps);
      atomicAdd(&rowstats[2 * (m0 + r) + 1], pq);
    }
  }
  {
    int r = tid >> 3, c8 = (tid & 7) * 8;   // 32 rows x 64 k, one bf16x8 per thread
    *(bf16x8*)&Bw[r * 72 + c8] = *(const bf16x8*)&WhS[(size_t)r * FD + c0 + c8];
  }
  __syncthreads();
  // epilogue 3: logits slice = tmp_tile(128x64) @ WhS_slice(32x64)^T, atomic into lpart
  {
    int wm2 = w * 32;
    f32x4 lacc[2][2] = {};
    for (int ks = 0; ks < 2; ++ks) {
      bf16x8 af2[2], bf2[2];
      for (int i = 0; i < 2; ++i) {
        int rr = wm2 + i * 16 + lm;
        af2[i] = *(const bf16x8*)&Co[swzs(rr, ks * 32 + lq * 8)];
      }
      for (int j = 0; j < 2; ++j)
        bf2[j] = *(const bf16x8*)&Bw[(j * 16 + lm) * 72 + ks * 32 + lq * 8];
      for (int i = 0; i < 2; ++i)
        for (int j = 0; j < 2; ++j)
          lacc[i][j] = __builtin_amdgcn_mfma_f32_16x16x32_bf16(af2[i], bf2[j], lacc[i][j], 0, 0, 0);
    }
    float* lp = lpart + (size_t)(blockIdx.y & (LSLICE - 1)) * BB * FF;
    for (int i = 0; i < 2; ++i)
      for (int j = 0; j < 2; ++j)
        for (int v = 0; v < 4; ++v) {
          int r = wm2 + i * 16 + lq * 4 + v;
          int c = j * 16 + lm;
          atomicAdd(&lp[(size_t)(m0 + r) * FF + c], lacc[i][j][v]);
        }
  }
}

// ---------------- fused: combine lpart slices + affine + softmax + weighted select ----------------
__global__ __launch_bounds__(128) void select_fused(
    const float* __restrict__ lpart, const float* __restrict__ rowstats,
    const float* __restrict__ u, const float* __restrict__ w0,
    const short* __restrict__ stacked, float* __restrict__ outsel,
    float* __restrict__ outw) {
  __shared__ float wf[FF];
  __shared__ short L[FD];
  int b = blockIdx.x;
  int t = threadIdx.x;
  for (int i = 0; i < 4; ++i) {
    int idx = t + 128 * i;
    *(bf16x8*)&L[idx * 8] = *(const bf16x8*)&stacked[(size_t)b * FD + idx * 8];
  }
  if (t < 32) {
    float s = 0.f;
    for (int p = 0; p < LSLICE; ++p) s += lpart[(size_t)p * BB * FF + (size_t)b * FF + t];
    float tot  = rowstats[2 * b];
    float totq = rowstats[2 * b + 1];
    float mu = tot * (1.f / FD);
    float var = totq * (1.f / FD) - mu * mu;
    float rstd = rsqrtf(var + LN_EPS);
    float l = rstd * s - mu * rstd * u[t] + w0[t];
    float m = l;
    for (int off = 16; off; off >>= 1) m = fmaxf(m, __shfl_xor(m, off, 32));
    float e = __builtin_amdgcn_exp2f(L2E * (l - m));
    float ss = e;
    for (int off = 16; off; off >>= 1) ss += __shfl_xor(ss, off, 32);
    float wv = e / ss;
    wf[t] = wv;
    outw[(size_t)b * FF + t] = wv;
  }
  __syncthreads();
  float acc = 0.f;
  for (int ff = 0; ff < FF; ++ff) acc += s2f(L[ff * 128 + t]) * wf[ff];
  outsel[(size_t)b * DD + t] = acc;
}

extern "C" void kernel_launch(void* const* d_in, const int* in_sizes, int n_in,
                              void* d_out, int out_size, void* d_ws, size_t ws_size,
                              hipStream_t stream) {
  const float* x   = (const float*)d_in[0];
  const float* Wp  = (const float*)d_in[1];
  const float* bp  = (const float*)d_in[2];
  const float* fW1 = (const float*)d_in[3];
  const float* fb1 = (const float*)d_in[4];
  const float* fW2 = (const float*)d_in[5];
  const float* fb2 = (const float*)d_in[6];
  const float* fWg = (const float*)d_in[7];
  const float* fbg = (const float*)d_in[8];
  const float* fg  = (const float*)d_in[9];
  const float* fbe = (const float*)d_in[10];
  const float* sW1 = (const float*)d_in[11];
  const float* sb1 = (const float*)d_in[12];
  const float* sW2 = (const float*)d_in[13];
  const float* sb2 = (const float*)d_in[14];
  const float* sWg = (const float*)d_in[15];
  const float* sbg = (const float*)d_in[16];
  const float* sg  = (const float*)d_in[17];
  const float* sbe = (const float*)d_in[18];
  const float* Wh  = (const float*)d_in[19];
  const float* bh  = (const float*)d_in[20];

  float* w = (float*)d_ws;
  size_t off = 0;
  float* A1   = w + off; off += (size_t)FF * HH;
  float* C1   = w + off; off += (size_t)FF * HH;
  float* c2   = w + off; off += (size_t)FF * E2;
  float* c3   = w + off; off += (size_t)F2;
  float* rowstats = w + off; off += (size_t)2 * BB;
  float* u    = w + off; off += 32;
  float* w0   = w + off; off += 32;
  float* M2   = w + off; off += (size_t)FF * HH * E2;               // 4 MB
  float* partial = w + off; off += (size_t)KSPLIT * BB * 128;       // 32 MB
  float* lpart = w + off; off += (size_t)LSLICE * BB * FF;          // 8 MB
  short* hh1  = (short*)(w + off); off += (size_t)BB * 128 / 2;     // 2 MB
  short* M3T  = (short*)(w + off); off += (size_t)F2 * 128 / 2;     // 2 MB
  short* sW2b = (short*)(w + off); off += (size_t)128 * FD / 2;     // 1 MB
  short* sW1T = (short*)(w + off); off += (size_t)128 * FD / 2;     // 1 MB
  short* M2T  = (short*)(w + off); off += (size_t)FF * E2 * HH / 2; // 2 MB
  short* WhS  = (short*)(w + off); off += (size_t)FF * FD / 2;      // 256 KB
  short* stacked = (short*)(w + off); off += (size_t)BB * FD / 2;   // 64 MB
  short* sWgT = (short*)(w + off); off += (size_t)F2 * FD / 2;      // 64 MB

  float* outsel = (float*)d_out;
  float* outw   = outsel + (size_t)BB * DD;

  // --- prep / casts ---
  cast_bf16<<<(128 * FD + 255) / 256, 256, 0, stream>>>(sW2, sW2b, 128 * FD);
  castT<<<dim3(DD / 64, FD / 64), 256, 0, stream>>>(sW1, sW1T, FD, DD);
  init_misc<<<(LSLICE * BB * FF) / 256, 256, 0, stream>>>(sbg, bh, c3, rowstats, u, w0, lpart);
  castT_c3<<<dim3(F2 / 64, FD / 64), 256, 0, stream>>>(sWg, sWgT, sb2, c3);
  prep_whs<<<FD / 64, 256, 0, stream>>>(Wh, sg, sbe, WhS, u, w0);
  // --- G1: M3T = (sW2 @ sWg)^T ---
  gemm_bt_n128_splitk<<<dim3(F2 / 128, KSPLIT), 256, 0, stream>>>(sWgT, sW2b, partial, F2, FD);
  reduce_m3t<<<(F2 * 128) / 256, 256, 0, stream>>>(partial, M3T, F2);
  // --- per-feature GRN prep + stage A (MFMA) ---
  prep_A1<<<FF, 128, 0, stream>>>(Wp, bp, fW1, fb1, A1, C1);
  prep_M2<<<dim3(FF, HH), E2, 0, stream>>>(fW2, fWg, M2);
  m2_castT<<<dim3(HH / 64, E2 / 64, FF), 256, 0, stream>>>(M2, M2T);
  prep_c2<<<FF, E2, 0, stream>>>(fb2, fWg, fbg, c2);
  stageA_mfma<<<dim3(BB / 64, FF), 256, 0, stream>>>(x, Wp, bp, A1, C1, M2T, c2, fg, fbe,
                                                     stacked);
  // --- G2: hh1 = elu(stacked @ sW1 + sb1) ---
  gemm_bt_n128_splitk<<<dim3(BB / 128, KSPLIT), 256, 0, stream>>>(stacked, sW1T, partial, BB, FD);
  reduce_hh1<<<(BB * 128) / 256, 256, 0, stream>>>(partial, sb1, hh1, BB);
  // --- G3+logits fused: gates, tmp (LDS-only), LN stats, logits partials ---
  sgate_mfma<<<dim3(BB / 128, FD / 64), 256, 0, stream>>>(hh1, M3T, c3, stacked, WhS,
                                                          rowstats, lpart);
  // --- fused softmax/select (LN finalize + lpart combine inside) ---
  select_fused<<<BB, 128, 0, stream>>>(lpart, rowstats, u, w0, stacked, outsel, outw);
}

// Round 9
// 476.398 us; speedup vs baseline: 1.0756x; 1.0756x over previous
//
#include <hip/hip_runtime.h>
#include <hip/hip_bf16.h>
#include <math.h>

#define BB 8192
#define FF 32
#define DD 128
#define HH 128
#define FD 4096   // F*D
#define E2 256    // 2*D
#define F2 8192   // 2*FD
#define LN_EPS 1e-5f
#define L2E 1.44269504f
#define KSPLIT 8

typedef __hip_bfloat16 bf16;
typedef __attribute__((ext_vector_type(8))) short bf16x8;
typedef __attribute__((ext_vector_type(4))) float f32x4;

__device__ __forceinline__ float s2f(short s) {
  union { float f; unsigned u; } x; x.u = ((unsigned)(unsigned short)s) << 16; return x.f;
}
__device__ __forceinline__ short f2s(float v) {
  bf16 h = __float2bfloat16(v); return *(short*)&h;
}
__device__ __forceinline__ float fast_sigmoid(float s) {
  return __builtin_amdgcn_rcpf(1.f + __builtin_amdgcn_exp2f(-L2E * s));
}
__device__ __forceinline__ float fast_elu(float v) {
  return v > 0.f ? v : __builtin_amdgcn_exp2f(L2E * v) - 1.f;
}

// byte offset into a [rows][64] bf16 tile (128B rows) with XOR swizzle; hb = byte offset
// within row. XOR only touches bits 4-6 so any alignment >= the access size is kept.
__device__ __forceinline__ int swz64(int row, int hb) {
  return row * 128 + (hb ^ ((row & 7) << 4));
}

// ---------------- prep kernels (inputs fp32) ----------------

__global__ void prep_A1(const float* __restrict__ Wp, const float* __restrict__ bp,
                        const float* __restrict__ fW1, const float* __restrict__ fb1,
                        float* __restrict__ A1, float* __restrict__ C1) {
  int f = blockIdx.x, h = threadIdx.x;
  const float* w1 = fW1 + (size_t)f * DD * HH;
  float a = 0.f, c = 0.f;
  for (int d = 0; d < DD; ++d) {
    float w = w1[d * HH + h];
    a += Wp[f * DD + d] * w;
    c += bp[f * DD + d] * w;
  }
  A1[f * HH + h] = a;
  C1[f * HH + h] = c + fb1[f * HH + h];
}

__global__ void prep_M2(const float* __restrict__ fW2, const float* __restrict__ fWg,
                        float* __restrict__ M2) {
  int f = blockIdx.x, h = blockIdx.y, e = threadIdx.x;
  const float* w2 = fW2 + ((size_t)f * HH + h) * DD;
  const float* wg = fWg + (size_t)f * DD * E2;
  float acc = 0.f;
  for (int d = 0; d < DD; ++d) acc += w2[d] * wg[d * E2 + e];
  M2[((size_t)f * HH + h) * E2 + e] = acc;
}

// M2 [f][h][e] fp32 -> M2T [f][e][h] bf16 (float4 loads, bf16x8 stores)
__global__ void m2_castT(const float* __restrict__ M2, short* __restrict__ M2T) {
  __shared__ float T[64][65];
  int h0 = blockIdx.x * 64, e0 = blockIdx.y * 64, f = blockIdx.z;
  int t = threadIdx.x;
  for (int i = 0; i < 4; ++i) {
    int lin = t + 256 * i;
    int r = lin >> 4, c4 = (lin & 15) * 4;
    f32x4 v = *(const f32x4*)&M2[((size_t)f * HH + h0 + r) * E2 + e0 + c4];
    T[r][c4] = v[0]; T[r][c4 + 1] = v[1]; T[r][c4 + 2] = v[2]; T[r][c4 + 3] = v[3];
  }
  __syncthreads();
  for (int i = 0; i < 2; ++i) {
    int lin = t + 256 * i;
    int e = lin >> 3, h8 = (lin & 7) * 8;
    short o[8];
    for (int k = 0; k < 8; ++k) o[k] = f2s(T[h8 + k][e]);
    *(bf16x8*)&M2T[((size_t)f * E2 + e0 + e) * HH + h0 + h8] = *(bf16x8*)&o[0];
  }
}

__global__ void prep_c2(const float* __restrict__ fb2, const float* __restrict__ fWg,
                        const float* __restrict__ fbg, float* __restrict__ c2) {
  int f = blockIdx.x, e = threadIdx.x;
  const float* wg = fWg + (size_t)f * DD * E2;
  float acc = 0.f;
  for (int d = 0; d < DD; ++d) acc += fb2[f * DD + d] * wg[d * E2 + e];
  c2[f * E2 + e] = acc + fbg[f * E2 + e];
}

__global__ void cast_bf16(const float* __restrict__ in, short* __restrict__ out, int n) {
  int i = blockIdx.x * 256 + threadIdx.x;
  if (i < n) out[i] = f2s(in[i]);
}

// transpose-cast: in (R x C) fp32 -> out (C x R) bf16 (float4 loads, bf16x8 stores)
__global__ void castT(const float* __restrict__ in, short* __restrict__ out, int R, int C) {
  __shared__ float T[64][65];
  int c0 = blockIdx.x * 64, r0 = blockIdx.y * 64;
  int t = threadIdx.x;
  for (int i = 0; i < 4; ++i) {
    int lin = t + 256 * i;
    int r = lin >> 4, c4 = (lin & 15) * 4;
    f32x4 v = *(const f32x4*)&in[(size_t)(r0 + r) * C + c0 + c4];
    T[r][c4] = v[0]; T[r][c4 + 1] = v[1]; T[r][c4 + 2] = v[2]; T[r][c4 + 3] = v[3];
  }
  __syncthreads();
  for (int i = 0; i < 2; ++i) {
    int lin = t + 256 * i;
    int c = lin >> 3, r8 = (lin & 7) * 8;
    short o[8];
    for (int e = 0; e < 8; ++e) o[e] = f2s(T[r8 + e][c]);
    *(bf16x8*)&out[(size_t)(c0 + c) * R + r0 + r8] = *(bf16x8*)&o[0];
  }
}

// merged tiny inits: c3 = sbg; rowstats = 0; u = 0; w0 = bh   (grid F2/256)
__global__ void init_misc(const float* __restrict__ sbg, const float* __restrict__ bh,
                          float* __restrict__ c3, float* __restrict__ rowstats,
                          float* __restrict__ u, float* __restrict__ w0) {
  int j = blockIdx.x * 256 + threadIdx.x;
  c3[j] = sbg[j];
  rowstats[2 * j] = 0.f;
  rowstats[2 * j + 1] = 0.f;
  if (j < 32) { u[j] = 0.f; w0[j] = bh[j]; }
}

// WhS = (sg*Wh)^T bf16; u += sg.Wh col-sums; w0 += sbe.Wh col-sums
__global__ void prep_whs(const float* __restrict__ Wh, const float* __restrict__ sg,
                         const float* __restrict__ sbe, short* __restrict__ WhS,
                         float* __restrict__ u, float* __restrict__ w0) {
  __shared__ float T[64][33];
  int k0 = blockIdx.x * 64;
  int t = threadIdx.x;
  {
    int k = t >> 5, c = t & 31;
    for (int i = 0; i < 8; ++i)
      T[k + 8 * i][c] = Wh[(size_t)(k0 + k + 8 * i) * FF + c];
  }
  __syncthreads();
  {
    int c = t >> 3, kk = (t & 7) * 8;
    short o[8];
    for (int i = 0; i < 8; ++i) o[i] = f2s(sg[k0 + kk + i] * T[kk + i][c]);
    *(bf16x8*)&WhS[(size_t)c * FD + k0 + kk] = *(bf16x8*)&o[0];
  }
  if (t < 32) {
    float su = 0.f, sw = 0.f;
    for (int k = 0; k < 64; ++k) { su += sg[k0 + k] * T[k][t]; sw += sbe[k0 + k] * T[k][t]; }
    atomicAdd(&u[t], su);
    atomicAdd(&w0[t], sw);
  }
}

// ---------------- G1 fused: partial = sWg^T @ sW2b^T (transpose folded into A-staging) ----
// v10: reads sWg (fp32) DIRECTLY -- deletes castT_c3 (128MB read + 64MB write) and the
// 64MB sWgT buffer. Each 64k x 128e chunk: coalesced f32x4 reads along e, bf16 scalar
// scatter into the swizzled As tile. Also folds c3 += sb2 @ sWg: per-thread register
// accumulation (each sWg element visited exactly once grid-wide), flushed with ~1K
// atomics/block (0.5M total -- v9's 17M-atomic lesson: keep atomic volume small).
__global__ __launch_bounds__(256) void gemm_m3t_fused(
    const float* __restrict__ sWg, const short* __restrict__ sW2b,
    const float* __restrict__ sb2, float* __restrict__ Cp, float* __restrict__ c3) {
  __shared__ __align__(16) char As[128 * 128];  // [128e][64k] bf16, swizzled (16KB)
  __shared__ short Bs[128 * 72];                // 18KB
  int m0 = blockIdx.x * 128;                    // e-range
  int kchunk = FD >> 3;                         // 512
  int kbase = blockIdx.y * kchunk;
  int tid = threadIdx.x;
  int lane = tid & 63, w = tid >> 6;
  int wm = (w >> 1) * 64, wn = (w & 1) * 64;
  int lm = lane & 15, lq = lane >> 4;
  int q = tid & 31;      // e-quad: e = 4q + j
  int k0t = tid >> 5;    // 0..7
  f32x4 acc[4][4] = {};
  float c3p[4] = {0.f, 0.f, 0.f, 0.f};
  for (int kc = 0; kc < kchunk; kc += 64) {
    for (int i = 0; i < 4; ++i) {
      int li = tid + 256 * i;
      int r = li >> 3, c8 = (li & 7) * 8;
      *(bf16x8*)&Bs[r * 72 + c8] = *(const bf16x8*)&sW2b[(size_t)r * FD + kbase + kc + c8];
    }
    for (int i = 0; i < 8; ++i) {
      int kk = k0t + 8 * i;                 // k within chunk
      int k = kbase + kc + kk;
      f32x4 v = *(const f32x4*)&sWg[(size_t)k * F2 + m0 + 4 * q];
      float sb = sb2[k];
      for (int j = 0; j < 4; ++j) {
        c3p[j] = fmaf(sb, v[j], c3p[j]);
        *(short*)(As + swz64(4 * q + j, kk * 2)) = f2s(v[j]);
      }
    }
    __syncthreads();
    for (int ks = 0; ks < 2; ++ks) {
      bf16x8 af[4], bfr[4];
      int hb = ks * 64 + lq * 16;
      for (int i = 0; i < 4; ++i)
        af[i] = *(const bf16x8*)(As + swz64(wm + i * 16 + lm, hb));
      for (int j = 0; j < 4; ++j)
        bfr[j] = *(const bf16x8*)&Bs[(wn + j * 16 + lm) * 72 + ks * 32 + lq * 8];
      for (int i = 0; i < 4; ++i)
        for (int j = 0; j < 4; ++j)
          acc[i][j] = __builtin_amdgcn_mfma_f32_16x16x32_bf16(af[i], bfr[j], acc[i][j], 0, 0, 0);
    }
    __syncthreads();
  }
  for (int j = 0; j < 4; ++j) atomicAdd(&c3[m0 + 4 * q + j], c3p[j]);
  float* out = Cp + (size_t)blockIdx.y * F2 * 128;
  for (int i = 0; i < 4; ++i)
    for (int j = 0; j < 4; ++j)
      for (int v = 0; v < 4; ++v) {
        int r = wm + i * 16 + lq * 4 + v;
        int c = wn + j * 16 + lm;
        out[(size_t)(m0 + r) * 128 + c] = acc[i][j][v];
      }
}

// ---------------- MFMA GEMM: C[M,128] = A[M,K] @ BT[128,K]^T, split-K by 8 ----------------
__global__ __launch_bounds__(256) void gemm_bt_n128_splitk(
    const short* __restrict__ A, const short* __restrict__ BT,
    float* __restrict__ Cp, int M, int K) {
  __shared__ short As[128 * 72];
  __shared__ short Bs[128 * 72];
  int m0 = blockIdx.x * 128;
  int kchunk = K >> 3;
  int kbase = blockIdx.y * kchunk;
  int tid = threadIdx.x;
  int lane = tid & 63, w = tid >> 6;
  int wm = (w >> 1) * 64, wn = (w & 1) * 64;
  int lm = lane & 15, lq = lane >> 4;
  f32x4 acc[4][4] = {};
  for (int kc = 0; kc < kchunk; kc += 64) {
    for (int i = 0; i < 4; ++i) {
      int li = tid + 256 * i;
      int r = li >> 3, c8 = (li & 7) * 8;
      *(bf16x8*)&As[r * 72 + c8] = *(const bf16x8*)&A[(size_t)(m0 + r) * K + kbase + kc + c8];
      *(bf16x8*)&Bs[r * 72 + c8] = *(const bf16x8*)&BT[(size_t)r * K + kbase + kc + c8];
    }
    __syncthreads();
    for (int ks = 0; ks < 2; ++ks) {
      bf16x8 af[4], bfr[4];
      for (int i = 0; i < 4; ++i)
        af[i] = *(const bf16x8*)&As[(wm + i * 16 + lm) * 72 + ks * 32 + lq * 8];
      for (int j = 0; j < 4; ++j)
        bfr[j] = *(const bf16x8*)&Bs[(wn + j * 16 + lm) * 72 + ks * 32 + lq * 8];
      for (int i = 0; i < 4; ++i)
        for (int j = 0; j < 4; ++j)
          acc[i][j] = __builtin_amdgcn_mfma_f32_16x16x32_bf16(af[i], bfr[j], acc[i][j], 0, 0, 0);
    }
    __syncthreads();
  }
  float* out = Cp + (size_t)blockIdx.y * M * 128;
  for (int i = 0; i < 4; ++i)
    for (int j = 0; j < 4; ++j)
      for (int v = 0; v < 4; ++v) {
        int r = wm + i * 16 + lq * 4 + v;
        int c = wn + j * 16 + lm;
        out[(size_t)(m0 + r) * 128 + c] = acc[i][j][v];
      }
}

__global__ void reduce_m3t(const float* __restrict__ Cp, short* __restrict__ M3T, int M) {
  size_t i = (size_t)blockIdx.x * 256 + threadIdx.x;
  float s = 0.f;
  for (int k = 0; k < KSPLIT; ++k) s += Cp[(size_t)k * M * 128 + i];
  M3T[i] = f2s(s);
}

__global__ void reduce_hh1(const float* __restrict__ Cp, const float* __restrict__ sb1,
                           short* __restrict__ hh1, int M) {
  size_t i = (size_t)blockIdx.x * 256 + threadIdx.x;
  float s = 0.f;
  for (int k = 0; k < KSPLIT; ++k) s += Cp[(size_t)k * M * 128 + i];
  s += sb1[i & 127];
  hh1[i] = f2s(fast_elu(s));
}

// ---------------- stage A (MFMA): h1 = elu(x*A1+C1); gates = h1@M2; LN -> stacked ----------------
// v8 structure: two-pass B time-share, one 16KB B-buffer, af held in regs across passes.
// No launch-bound clamp (v2/v4 lesson: clamping this kernel always spills).
__global__ __launch_bounds__(256) void stageA_mfma(
    const float* __restrict__ x, const float* __restrict__ Wp,
    const float* __restrict__ bp, const float* __restrict__ A1,
    const float* __restrict__ C1, const short* __restrict__ M2T,
    const float* __restrict__ c2, const float* __restrict__ fg,
    const float* __restrict__ fbe, short* __restrict__ stacked) {
  __shared__ __align__(16) char SM[(64 + 128) * 128];  // As(8K) | Bs(16K)
  char* As = SM;
  char* Bs = SM + 64 * 128;
  short* Co = (short*)(SM + 64 * 128); // epilogue 64x128 bf16 tile (16KB) aliases Bs
  float* red = (float*)SM;             // epilogue [2][64][2] stats (1KB) aliases As
  __shared__ float xsh[64];
  int f = blockIdx.y;
  int m0 = blockIdx.x * 64;
  int tid = threadIdx.x;
  int lane = tid & 63, w = tid >> 6;
  int wm = (w >> 1) * 32, wn = (w & 1) * 64;
  int lm = lane & 15, lq = lane >> 4;
  if (tid < 64) xsh[tid] = x[(size_t)(m0 + tid) * FF + f];
  __syncthreads();
  f32x4 accA[2][4] = {}, accB[2][4] = {};
  int c8 = (tid & 7) * 8, rb = tid >> 3;   // As-gen ownership: 8 cols x 2 rows per thread
  for (int kc = 0; kc < HH; kc += 64) {
    {
      f32x4 a1lo = *(const f32x4*)&A1[f * HH + kc + c8];
      f32x4 a1hi = *(const f32x4*)&A1[f * HH + kc + c8 + 4];
      f32x4 c1lo = *(const f32x4*)&C1[f * HH + kc + c8];
      f32x4 c1hi = *(const f32x4*)&C1[f * HH + kc + c8 + 4];
      for (int rr = 0; rr < 2; ++rr) {
        int row = rb + rr * 32;
        float xr = xsh[row];
        short o[8];
        for (int e = 0; e < 4; ++e) {
          o[e]     = f2s(fast_elu(fmaf(xr, a1lo[e], c1lo[e])));
          o[e + 4] = f2s(fast_elu(fmaf(xr, a1hi[e], c1hi[e])));
        }
        *(bf16x8*)(As + swz64(row, c8 * 2)) = *(bf16x8*)&o[0];
      }
    }
    for (int i = 0; i < 4; ++i) {
      int li = tid + 256 * i;
      int r = li >> 3, cc = (li & 7) * 8;
      bf16x8 va = *(const bf16x8*)&M2T[((size_t)f * E2 + r) * HH + kc + cc];
      *(bf16x8*)(Bs + swz64(r, cc * 2)) = va;
    }
    __syncthreads();
    bf16x8 af[2][2];
    for (int ks = 0; ks < 2; ++ks)
      for (int i = 0; i < 2; ++i)
        af[ks][i] = *(const bf16x8*)(As + swz64(wm + i * 16 + lm, ks * 64 + lq * 16));
    for (int ks = 0; ks < 2; ++ks) {
      int hb = ks * 64 + lq * 16;
      for (int j = 0; j < 4; ++j) {
        bf16x8 ba = *(const bf16x8*)(Bs + swz64(wn + j * 16 + lm, hb));
        for (int i = 0; i < 2; ++i)
          accA[i][j] = __builtin_amdgcn_mfma_f32_16x16x32_bf16(af[ks][i], ba, accA[i][j], 0, 0, 0);
      }
    }
    __syncthreads();
    for (int i = 0; i < 4; ++i) {
      int li = tid + 256 * i;
      int r = li >> 3, cc = (li & 7) * 8;
      bf16x8 vb = *(const bf16x8*)&M2T[((size_t)f * E2 + 128 + r) * HH + kc + cc];
      *(bf16x8*)(Bs + swz64(r, cc * 2)) = vb;
    }
    __syncthreads();
    for (int ks = 0; ks < 2; ++ks) {
      int hb = ks * 64 + lq * 16;
      for (int j = 0; j < 4; ++j) {
        bf16x8 bb = *(const bf16x8*)(Bs + swz64(wn + j * 16 + lm, hb));
        for (int i = 0; i < 2; ++i)
          accB[i][j] = __builtin_amdgcn_mfma_f32_16x16x32_bf16(af[ks][i], bb, accB[i][j], 0, 0, 0);
      }
    }
    __syncthreads();
  }
  float c2a[4], c2s[4], wpv[4], bpv[4];
  for (int j = 0; j < 4; ++j) {
    int c = wn + j * 16 + lm;
    c2a[j] = c2[f * E2 + c];
    c2s[j] = c2[f * E2 + 128 + c];
    wpv[j] = Wp[f * DD + c];
    bpv[j] = bp[f * DD + c];
  }
  float rs[2][4], rq[2][4];
  for (int i = 0; i < 2; ++i)
    for (int v = 0; v < 4; ++v) {
      int r = wm + i * 16 + lq * 4 + v;
      float xr = xsh[r];
      float sum = 0.f, sq = 0.f;
      for (int j = 0; j < 4; ++j) {
        float a = accA[i][j][v] + c2a[j];
        float s = accB[i][j][v] + c2s[j];
        float emb = fmaf(xr, wpv[j], bpv[j]);
        float y = fmaf(a, fast_sigmoid(s), emb);
        accA[i][j][v] = y;  // stash y
        sum += y; sq += y * y;
      }
      rs[i][v] = sum; rq[i][v] = sq;
    }
  for (int m = 1; m < 16; m <<= 1)
    for (int i = 0; i < 2; ++i)
      for (int v = 0; v < 4; ++v) {
        rs[i][v] += __shfl_xor(rs[i][v], m, 64);
        rq[i][v] += __shfl_xor(rq[i][v], m, 64);
      }
  if (lm == 0)
    for (int i = 0; i < 2; ++i)
      for (int v = 0; v < 4; ++v) {
        int r = wm + i * 16 + lq * 4 + v;
        red[(w & 1) * 128 + r * 2]     = rs[i][v];
        red[(w & 1) * 128 + r * 2 + 1] = rq[i][v];
      }
  __syncthreads();
  float fgv[4], fbev[4];
  for (int j = 0; j < 4; ++j) {
    int c = wn + j * 16 + lm;
    fgv[j] = fg[f * DD + c];
    fbev[j] = fbe[f * DD + c];
  }
  for (int i = 0; i < 2; ++i)
    for (int v = 0; v < 4; ++v) {
      int r = wm + i * 16 + lq * 4 + v;
      float tot  = red[r * 2]     + red[128 + r * 2];
      float totq = red[r * 2 + 1] + red[128 + r * 2 + 1];
      float mu = tot * (1.f / DD);
      float var = totq * (1.f / DD) - mu * mu;
      float rstd = rsqrtf(var + LN_EPS);
      for (int j = 0; j < 4; ++j) {
        int c = wn + j * 16 + lm;
        Co[r * 128 + c] = f2s((accA[i][j][v] - mu) * rstd * fgv[j] + fbev[j]);
      }
    }
  __syncthreads();
  for (int i = 0; i < 4; ++i) {
    int lin = tid + 256 * i;
    int r = lin >> 4, cc8 = (lin & 15) * 8;
    *(bf16x8*)&stacked[((size_t)(m0 + r) * FF + f) * DD + cc8] = *(bf16x8*)&Co[r * 128 + cc8];
  }
}

// ---------------- sgate MFMA: gates = hh1 @ M3 (+c3), tmp = stacked + sa*sigmoid(ss) ----------------
// v8 form (restored from v9's atomic-heavy fusion): tmp to global, LN partial stats
// fused via ~1M atomics (v5-validated).
__global__ __launch_bounds__(256) void sgate_mfma(
    const short* __restrict__ hh1, const short* __restrict__ M3T,
    const float* __restrict__ c3, const short* __restrict__ stacked,
    short* __restrict__ tmp, float* __restrict__ rowstats) {
  __shared__ short As[128 * 72];
  __shared__ short Ba[64 * 72];
  __shared__ short Bb[64 * 72];
  short* Co = As;  // epilogue alias: 128x64 bf16 tile (16KB <= 18KB)
  int m0 = blockIdx.x * 128;
  int c0 = blockIdx.y * 64;
  int tid = threadIdx.x;
  int lane = tid & 63, w = tid >> 6;
  int wm = (w >> 1) * 64, wn = (w & 1) * 32;
  int lm = lane & 15, lq = lane >> 4;
  f32x4 accA[4][2] = {}, accB[4][2] = {};
  for (int kc = 0; kc < 128; kc += 64) {
    for (int i = 0; i < 4; ++i) {
      int li = tid + 256 * i;
      int r = li >> 3, c8 = (li & 7) * 8;
      *(bf16x8*)&As[r * 72 + c8] = *(const bf16x8*)&hh1[(size_t)(m0 + r) * 128 + kc + c8];
    }
    for (int i = 0; i < 2; ++i) {
      int li = tid + 256 * i;
      int r = li >> 3, c8 = (li & 7) * 8;
      *(bf16x8*)&Ba[r * 72 + c8] = *(const bf16x8*)&M3T[(size_t)(c0 + r) * 128 + kc + c8];
      *(bf16x8*)&Bb[r * 72 + c8] = *(const bf16x8*)&M3T[(size_t)(4096 + c0 + r) * 128 + kc + c8];
    }
    __syncthreads();
    for (int ks = 0; ks < 2; ++ks) {
      bf16x8 af[4], ba[2], bb[2];
      for (int i = 0; i < 4; ++i)
        af[i] = *(const bf16x8*)&As[(wm + i * 16 + lm) * 72 + ks * 32 + lq * 8];
      for (int j = 0; j < 2; ++j) {
        ba[j] = *(const bf16x8*)&Ba[(wn + j * 16 + lm) * 72 + ks * 32 + lq * 8];
        bb[j] = *(const bf16x8*)&Bb[(wn + j * 16 + lm) * 72 + ks * 32 + lq * 8];
      }
      for (int i = 0; i < 4; ++i)
        for (int j = 0; j < 2; ++j) {
          accA[i][j] = __builtin_amdgcn_mfma_f32_16x16x32_bf16(af[i], ba[j], accA[i][j], 0, 0, 0);
          accB[i][j] = __builtin_amdgcn_mfma_f32_16x16x32_bf16(af[i], bb[j], accB[i][j], 0, 0, 0);
        }
    }
    __syncthreads();
  }
  for (int i = 0; i < 4; ++i)
    for (int j = 0; j < 2; ++j)
      for (int v = 0; v < 4; ++v) {
        int rl = wm + i * 16 + lq * 4 + v;
        int cl = wn + j * 16 + lm;
        int c = c0 + cl;
        float sa = accA[i][j][v] + c3[c];
        float ss = accB[i][j][v] + c3[c + 4096];
        Co[rl * 64 + cl] = f2s(sa * fast_sigmoid(ss));
      }
  __syncthreads();
  for (int i = 0; i < 4; ++i) {
    int lin = tid + 256 * i;
    int r = lin >> 3, c8 = (lin & 7) * 8;
    size_t gi = (size_t)(m0 + r) * FD + c0 + c8;
    bf16x8 sv = *(const bf16x8*)&stacked[gi];
    bf16x8 av = *(bf16x8*)&Co[r * 64 + c8];
    short ov[8];
    float ps = 0.f, pq = 0.f;
    for (int e = 0; e < 8; ++e) {
      short o = f2s(s2f(sv[e]) + s2f(av[e]));
      ov[e] = o;
      float vb = s2f(o);
      ps += vb; pq += vb * vb;
    }
    *(bf16x8*)&tmp[gi] = *(bf16x8*)&ov[0];
    ps += __shfl_xor(ps, 1, 64); pq += __shfl_xor(pq, 1, 64);
    ps += __shfl_xor(ps, 2, 64); pq += __shfl_xor(pq, 2, 64);
    ps += __shfl_xor(ps, 4, 64); pq += __shfl_xor(pq, 4, 64);
    if ((tid & 7) == 0) {
      atomicAdd(&rowstats[2 * (m0 + r)], ps);
      atomicAdd(&rowstats[2 * (m0 + r) + 1], pq);
    }
  }
}

// ---------------- logits GEMM (split-K by 8): partial = tmp @ WhS^T ----------------
__global__ __launch_bounds__(256) void gemm_logits_splitk(
    const short* __restrict__ tmp, const short* __restrict__ WhS,
    float* __restrict__ partial) {
  __shared__ short As[128 * 72];
  __shared__ short Bs[32 * 72];
  int m0 = blockIdx.x * 128;
  int kbase = blockIdx.y * (FD / 8);
  int tid = threadIdx.x;
  int lane = tid & 63, w = tid >> 6;
  int wm = w * 32;
  int lm = lane & 15, lq = lane >> 4;
  f32x4 acc[2][2] = {};
  for (int kc = 0; kc < FD / 8; kc += 64) {
    for (int i = 0; i < 4; ++i) {
      int li = tid + 256 * i;
      int r = li >> 3, c8 = (li & 7) * 8;
      *(bf16x8*)&As[r * 72 + c8] = *(const bf16x8*)&tmp[(size_t)(m0 + r) * FD + kbase + kc + c8];
    }
    {
      int r = tid >> 3, c8 = (tid & 7) * 8;
      if (r < 32)
        *(bf16x8*)&Bs[r * 72 + c8] = *(const bf16x8*)&WhS[(size_t)r * FD + kbase + kc + c8];
    }
    __syncthreads();
    for (int ks = 0; ks < 2; ++ks) {
      bf16x8 af[2], bfr[2];
      for (int i = 0; i < 2; ++i)
        af[i] = *(const bf16x8*)&As[(wm + i * 16 + lm) * 72 + ks * 32 + lq * 8];
      for (int j = 0; j < 2; ++j)
        bfr[j] = *(const bf16x8*)&Bs[(j * 16 + lm) * 72 + ks * 32 + lq * 8];
      for (int i = 0; i < 2; ++i)
        for (int j = 0; j < 2; ++j)
          acc[i][j] = __builtin_amdgcn_mfma_f32_16x16x32_bf16(af[i], bfr[j], acc[i][j], 0, 0, 0);
    }
    __syncthreads();
  }
  for (int i = 0; i < 2; ++i)
    for (int j = 0; j < 2; ++j)
      for (int v = 0; v < 4; ++v) {
        int r = m0 + wm + i * 16 + lq * 4 + v;
        int c = j * 16 + lm;
        partial[(size_t)blockIdx.y * BB * FF + (size_t)r * FF + c] = acc[i][j][v];
      }
}

// ---------------- fused: combine partials + affine + softmax + weighted select ----------------
__global__ __launch_bounds__(128) void select_fused(
    const float* __restrict__ partial, const float* __restrict__ rowstats,
    const float* __restrict__ u, const float* __restrict__ w0,
    const short* __restrict__ stacked, float* __restrict__ outsel,
    float* __restrict__ outw) {
  __shared__ float wf[FF];
  __shared__ short L[FD];
  int b = blockIdx.x;
  int t = threadIdx.x;
  for (int i = 0; i < 4; ++i) {
    int idx = t + 128 * i;
    *(bf16x8*)&L[idx * 8] = *(const bf16x8*)&stacked[(size_t)b * FD + idx * 8];
  }
  if (t < 32) {
    float s = 0.f;
    for (int p = 0; p < KSPLIT; ++p) s += partial[(size_t)p * BB * FF + (size_t)b * FF + t];
    float tot  = rowstats[2 * b];
    float totq = rowstats[2 * b + 1];
    float mu = tot * (1.f / FD);
    float var = totq * (1.f / FD) - mu * mu;
    float rstd = rsqrtf(var + LN_EPS);
    float l = rstd * s - mu * rstd * u[t] + w0[t];
    float m = l;
    for (int off = 16; off; off >>= 1) m = fmaxf(m, __shfl_xor(m, off, 32));
    float e = __builtin_amdgcn_exp2f(L2E * (l - m));
    float ss = e;
    for (int off = 16; off; off >>= 1) ss += __shfl_xor(ss, off, 32);
    float wv = e / ss;
    wf[t] = wv;
    outw[(size_t)b * FF + t] = wv;
  }
  __syncthreads();
  float acc = 0.f;
  for (int ff = 0; ff < FF; ++ff) acc += s2f(L[ff * 128 + t]) * wf[ff];
  outsel[(size_t)b * DD + t] = acc;
}

extern "C" void kernel_launch(void* const* d_in, const int* in_sizes, int n_in,
                              void* d_out, int out_size, void* d_ws, size_t ws_size,
                              hipStream_t stream) {
  const float* x   = (const float*)d_in[0];
  const float* Wp  = (const float*)d_in[1];
  const float* bp  = (const float*)d_in[2];
  const float* fW1 = (const float*)d_in[3];
  const float* fb1 = (const float*)d_in[4];
  const float* fW2 = (const float*)d_in[5];
  const float* fb2 = (const float*)d_in[6];
  const float* fWg = (const float*)d_in[7];
  const float* fbg = (const float*)d_in[8];
  const float* fg  = (const float*)d_in[9];
  const float* fbe = (const float*)d_in[10];
  const float* sW1 = (const float*)d_in[11];
  const float* sb1 = (const float*)d_in[12];
  const float* sW2 = (const float*)d_in[13];
  const float* sb2 = (const float*)d_in[14];
  const float* sWg = (const float*)d_in[15];
  const float* sbg = (const float*)d_in[16];
  const float* sg  = (const float*)d_in[17];
  const float* sbe = (const float*)d_in[18];
  const float* Wh  = (const float*)d_in[19];
  const float* bh  = (const float*)d_in[20];

  float* w = (float*)d_ws;
  size_t off = 0;
  float* A1   = w + off; off += (size_t)FF * HH;
  float* C1   = w + off; off += (size_t)FF * HH;
  float* c2   = w + off; off += (size_t)FF * E2;
  float* c3   = w + off; off += (size_t)F2;
  float* rowstats = w + off; off += (size_t)2 * BB;
  float* u    = w + off; off += 32;
  float* w0   = w + off; off += 32;
  float* M2   = w + off; off += (size_t)FF * HH * E2;               // 4 MB
  float* partial = w + off; off += (size_t)KSPLIT * BB * 128;       // 32 MB
  short* hh1  = (short*)(w + off); off += (size_t)BB * 128 / 2;     // 2 MB
  short* M3T  = (short*)(w + off); off += (size_t)F2 * 128 / 2;     // 2 MB
  short* sW2b = (short*)(w + off); off += (size_t)128 * FD / 2;     // 1 MB
  short* sW1T = (short*)(w + off); off += (size_t)128 * FD / 2;     // 1 MB
  short* M2T  = (short*)(w + off); off += (size_t)FF * E2 * HH / 2; // 2 MB
  short* WhS  = (short*)(w + off); off += (size_t)FF * FD / 2;      // 256 KB
  short* stacked = (short*)(w + off); off += (size_t)BB * FD / 2;   // 64 MB
  short* tmp  = (short*)(w + off); off += (size_t)BB * FD / 2;      // 64 MB

  float* outsel = (float*)d_out;
  float* outw   = outsel + (size_t)BB * DD;

  // --- prep / casts ---
  cast_bf16<<<(128 * FD + 255) / 256, 256, 0, stream>>>(sW2, sW2b, 128 * FD);
  castT<<<dim3(DD / 64, FD / 64), 256, 0, stream>>>(sW1, sW1T, FD, DD);
  init_misc<<<F2 / 256, 256, 0, stream>>>(sbg, bh, c3, rowstats, u, w0);
  prep_whs<<<FD / 64, 256, 0, stream>>>(Wh, sg, sbe, WhS, u, w0);
  // --- G1 fused: partial = sWg^T @ sW2b^T (direct from sWg) + c3 GEMV ---
  gemm_m3t_fused<<<dim3(F2 / 128, KSPLIT), 256, 0, stream>>>(sWg, sW2b, sb2, partial, c3);
  reduce_m3t<<<(F2 * 128) / 256, 256, 0, stream>>>(partial, M3T, F2);
  // --- per-feature GRN prep + stage A (MFMA) ---
  prep_A1<<<FF, 128, 0, stream>>>(Wp, bp, fW1, fb1, A1, C1);
  prep_M2<<<dim3(FF, HH), E2, 0, stream>>>(fW2, fWg, M2);
  m2_castT<<<dim3(HH / 64, E2 / 64, FF), 256, 0, stream>>>(M2, M2T);
  prep_c2<<<FF, E2, 0, stream>>>(fb2, fWg, fbg, c2);
  stageA_mfma<<<dim3(BB / 64, FF), 256, 0, stream>>>(x, Wp, bp, A1, C1, M2T, c2, fg, fbe,
                                                     stacked);
  // --- G2: hh1 = elu(stacked @ sW1 + sb1) ---
  gemm_bt_n128_splitk<<<dim3(BB / 128, KSPLIT), 256, 0, stream>>>(stacked, sW1T, partial, BB, FD);
  reduce_hh1<<<(BB * 128) / 256, 256, 0, stream>>>(partial, sb1, hh1, BB);
  // --- G3: tmp = stacked + sa*sigmoid(ss), fused LN partial stats ---
  sgate_mfma<<<dim3(BB / 128, FD / 64), 256, 0, stream>>>(hh1, M3T, c3, stacked, tmp, rowstats);
  // --- logits GEMM + fused softmax/select (LN finalize inside select_fused) ---
  gemm_logits_splitk<<<dim3(BB / 128, KSPLIT), 256, 0, stream>>>(tmp, WhS, partial);
  select_fused<<<BB, 128, 0, stream>>>(partial, rowstats, u, w0, stacked, outsel, outw);
}